// Round 9
// baseline (46818.661 us; speedup 1.0000x reference)
//
#include <hip/hip_runtime.h>

// MultiScaleGRU: T=8192, NINP=128, NSTATE=1024, NCH=4, GH=256, NLAYER=3, NCLASS=10
#define T_SEQ 8192
#define NST   1024
#define GHH   256
#define LD_IG 3072        // 4 channels * 768 ig columns
#define GW_OFF 167772160  // byte offset of f16 weight cache in ws (after bufG)

typedef _Float16 half8 __attribute__((ext_vector_type(8)));
typedef _Float16 f16x2 __attribute__((ext_vector_type(2)));
typedef float f32x4 __attribute__((ext_vector_type(4)));

#define MFMA16(a, b, c) __builtin_amdgcn_mfma_f32_16x16x32_f16(a, b, c, 0, 0, 0)

#if defined(__has_builtin)
#if __has_builtin(__builtin_amdgcn_fdot2)
#define HAVE_FDOT2 1
#endif
#endif

__device__ __forceinline__ float fdot2f(f16x2 a, f16x2 b, float c) {
#ifdef HAVE_FDOT2
  return __builtin_amdgcn_fdot2(a, b, c, false);
#else
  float d;
  asm("v_dot2_f32_f16 %0, %1, %2, %3" : "=v"(d) : "v"(a), "v"(b), "v"(c));
  return d;
#endif
}

// AGPR weight fetch, fixed mechanics (R8 post-mortem):
//  - NON-volatile: scheduler may interleave with MFMAs.
//  - dep operand (loop-variant) blocks LICM from hoisting all 96 reads out
//    of the loop (which would materialize 96 VGPRs -> pressure blowup).
__device__ __forceinline__ f16x2 aread_dep(unsigned int w, unsigned int dep) {
  unsigned int t;
  asm("v_accvgpr_read_b32 %0, %1" : "=v"(t) : "a"(w), "v"(dep));
  return __builtin_bit_cast(f16x2, t);
}

// quad-lane XOR butterfly add via DPP (VALU pipe)
template<int CTRL>
__device__ __forceinline__ float dpp_xor_add(float x) {
#if defined(__has_builtin) && __has_builtin(__builtin_amdgcn_update_dpp)
  int s = __builtin_amdgcn_update_dpp(0, __builtin_bit_cast(int, x), CTRL, 0xF, 0xF, true);
  return x + __builtin_bit_cast(float, s);
#else
  return x + __shfl_xor(x, (CTRL == 0xB1) ? 1 : 2, 64);
#endif
}

__device__ __forceinline__ float sigmoid_f(float x) {
  return 1.0f / (1.0f + __expf(-x));
}
__device__ __forceinline__ float tanh_f(float x) {
  float ax = fabsf(x);
  float e = __expf(-2.0f * ax);
  float t = (1.0f - e) / (1.0f + e);
  return copysignf(t, x);
}

// ---------------------------------------------------------------------------
// Prep A: whh rows 0..383 -> MFMA B-fragment cache (unchanged, R8-verified).
// ---------------------------------------------------------------------------
__global__ __launch_bounds__(256) void prep_whh(const float* __restrict__ whh,
                                                half8* __restrict__ wB)
{
  const int idx = blockIdx.x * 256 + threadIdx.x;   // 0 .. 147455
  const int lc  = idx / 12288;                      // layer*4+ch
  const int rem = idx - lc * 12288;
  const int g_id = rem >> 6, l = rem & 63;
  const int nb = g_id >> 3, kc = g_id & 7;          // nb 0..23 -> rows 0..383
  const int n = l & 15, kg = l >> 4;
  const int row = nb * 16 + n;
  const int col = kc * 32 + kg * 8;
  const float* src = whh + (size_t)lc * 196608 + (size_t)row * 256 + col;
  float4 x0 = *reinterpret_cast<const float4*>(src);
  float4 x1 = *reinterpret_cast<const float4*>(src + 4);
  half8 o;
  o[0] = (_Float16)x0.x; o[1] = (_Float16)x0.y;
  o[2] = (_Float16)x0.z; o[3] = (_Float16)x0.w;
  o[4] = (_Float16)x1.x; o[5] = (_Float16)x1.y;
  o[6] = (_Float16)x1.z; o[7] = (_Float16)x1.w;
  wB[(size_t)lc * 24576 + rem] = o;
}

// ---------------------------------------------------------------------------
// Prep B: whh rows 384..767 -> f16x2 pair cache (unchanged, R8-verified).
// ---------------------------------------------------------------------------
__global__ __launch_bounds__(256) void prep_vw(const float* __restrict__ whh,
                                               unsigned int* __restrict__ wv)
{
  const int idx = blockIdx.x * 256 + threadIdx.x;   // 0 .. 589823
  const int lc  = idx / 49152;
  const int r1  = idx - lc * 49152;
  const int q   = r1 >> 9, j = r1 & 511;
  const int m = q >> 5, pp = q & 31;
  const int s = j >> 2, c = j & 3;
  const int row = 384 + m * 128 + s;
  const int col = c * 64 + 2 * pp;
  const float* src = whh + (size_t)lc * 196608 + (size_t)row * 256 + col;
  f16x2 v = f16x2{(_Float16)src[0], (_Float16)src[1]};
  const size_t e16 = (size_t)lc * 24576 + 12288 + (size_t)(q >> 2) * 512 + j;
  wv[e16 * 4 + (q & 3)] = __builtin_bit_cast(unsigned int, v);
}

// ---------------------------------------------------------------------------
// f32 tiled GEMM (unchanged): C[M,N] = epi(A[M,K] @ W[N,K]^T).
// ---------------------------------------------------------------------------
template<int EPI, bool RELU>
__global__ __launch_bounds__(256) void gemm_f32(
    const float* __restrict__ A, const float* __restrict__ W,
    const float* __restrict__ bias, const float* __restrict__ R,
    float* __restrict__ C, int M, int N, int K,
    const float* __restrict__ log_s)
{
  const int BM = 64, BN = 64, BK = 16;
  __shared__ float As[BK][BM + 4];
  __shared__ float Ws[BK][BN + 4];
  const int bm = blockIdx.x * BM, bn = blockIdx.y * BN;
  const int t = threadIdx.x;
  const int tx = t & 15, ty = t >> 4;
  const int lm = t >> 2, lk = (t & 3) << 2;

  float acc[4][4] = {};
  const float* Ap = A + (size_t)(bm + lm) * K + lk;
  const float* Wp = W + (size_t)(bn + lm) * K + lk;

  for (int k0 = 0; k0 < K; k0 += BK) {
    float4 av = *reinterpret_cast<const float4*>(Ap + k0);
    float4 wv = *reinterpret_cast<const float4*>(Wp + k0);
    As[lk + 0][lm] = av.x; As[lk + 1][lm] = av.y;
    As[lk + 2][lm] = av.z; As[lk + 3][lm] = av.w;
    Ws[lk + 0][lm] = wv.x; Ws[lk + 1][lm] = wv.y;
    Ws[lk + 2][lm] = wv.z; Ws[lk + 3][lm] = wv.w;
    __syncthreads();
#pragma unroll
    for (int kk = 0; kk < BK; ++kk) {
      float4 a4 = *reinterpret_cast<const float4*>(&As[kk][ty << 2]);
      float4 w4 = *reinterpret_cast<const float4*>(&Ws[kk][tx << 2]);
      float a[4] = {a4.x, a4.y, a4.z, a4.w};
      float w[4] = {w4.x, w4.y, w4.z, w4.w};
#pragma unroll
      for (int i = 0; i < 4; ++i)
#pragma unroll
        for (int jj = 0; jj < 4; ++jj)
          acc[i][jj] = fmaf(a[i], w[jj], acc[i][jj]);
    }
    __syncthreads();
  }

  const int n0 = bn + (tx << 2);
  float b4[4];
#pragma unroll
  for (int jj = 0; jj < 4; ++jj) b4[jj] = bias[n0 + jj];
  float scale = 1.f;
  if (EPI == 1) {
    int chn = n0 / 768;
    float ls = log_s[chn];
    ls = fminf(fmaxf(ls, -10.f), 10.f);
    scale = __expf(-ls);
  }
#pragma unroll
  for (int i = 0; i < 4; ++i) {
    const int m = bm + (ty << 2) + i;
    float vals[4];
    float4 r4;
    if (EPI == 2) r4 = *reinterpret_cast<const float4*>(R + (size_t)m * N + n0);
#pragma unroll
    for (int jj = 0; jj < 4; ++jj) {
      float v = acc[i][jj];
      if (EPI == 1) v *= scale;
      v += b4[jj];
      if (EPI == 2) v += (jj == 0 ? r4.x : jj == 1 ? r4.y : jj == 2 ? r4.z : r4.w);
      if (RELU) v = fmaxf(v, 0.f);
      vals[jj] = v;
    }
    float4 o; o.x = vals[0]; o.y = vals[1]; o.z = vals[2]; o.w = vals[3];
    *reinterpret_cast<float4*>(C + (size_t)m * N + n0) = o;
  }
}

// ---------------------------------------------------------------------------
// LayerNorm over 1024 features (unchanged).
// ---------------------------------------------------------------------------
template<bool ADD>
__global__ __launch_bounds__(256) void ln_kernel(const float* __restrict__ X,
                                                 const float* __restrict__ Yad,
                                                 float* __restrict__ O)
{
  const int row = blockIdx.x, t = threadIdx.x;
  float4 v = reinterpret_cast<const float4*>(X + (size_t)row * NST)[t];
  if (ADD) {
    float4 w = reinterpret_cast<const float4*>(Yad + (size_t)row * NST)[t];
    v.x += w.x; v.y += w.y; v.z += w.z; v.w += w.w;
  }
  float s  = v.x + v.y + v.z + v.w;
  float ss = v.x * v.x + v.y * v.y + v.z * v.z + v.w * v.w;
#pragma unroll
  for (int m = 1; m < 64; m <<= 1) {
    s  += __shfl_xor(s, m, 64);
    ss += __shfl_xor(ss, m, 64);
  }
  __shared__ float ps[4], pss[4];
  const int wv = t >> 6;
  if ((t & 63) == 0) { ps[wv] = s; pss[wv] = ss; }
  __syncthreads();
  s  = ps[0] + ps[1] + ps[2] + ps[3];
  ss = pss[0] + pss[1] + pss[2] + pss[3];
  const float mean = s * (1.f / 1024.f);
  const float var  = ss * (1.f / 1024.f) - mean * mean;
  const float rstd = rsqrtf(var + 1e-5f);
  v.x = (v.x - mean) * rstd; v.y = (v.y - mean) * rstd;
  v.z = (v.z - mean) * rstd; v.w = (v.w - mean) * rstd;
  reinterpret_cast<float4*>(O + (size_t)row * NST)[t] = v;
}

// ---------------------------------------------------------------------------
// ScaleGRU scan v7 — dual-pipe with AGPR-HOMED dot2 weights.
// grid=4, 512 threads (8 waves, 2/SIMD). Wave: 3 MFMA blocks (rows 0..383,
// 24 frags = 96 AGPR) + per-thread 3 outputs x 32 f16x2 pairs (rows 384..767,
// 96 AGPR). vs R8: pairs are DEFINED by v_accvgpr_write asm ("=a") so their
// home class is AGPR (R8's "a"-input-only left home=scratch -> 13ms), reads
// are non-volatile (schedulable against MFMAs) and dep-tied to the h load
// (blocks LICM from hoisting 96 reads out of the loop).
// ---------------------------------------------------------------------------
#define SCAN_BAR() asm volatile("s_waitcnt lgkmcnt(0)\n\ts_barrier" ::: "memory")

#define DECLB(i) half8 B##i##_0, B##i##_1, B##i##_2, B##i##_3, \
                       B##i##_4, B##i##_5, B##i##_6, B##i##_7;
#define LOADB(i) \
  B##i##_0 = wp[((i)*8+0)*64]; B##i##_1 = wp[((i)*8+1)*64]; \
  B##i##_2 = wp[((i)*8+2)*64]; B##i##_3 = wp[((i)*8+3)*64]; \
  B##i##_4 = wp[((i)*8+4)*64]; B##i##_5 = wp[((i)*8+5)*64]; \
  B##i##_6 = wp[((i)*8+6)*64]; B##i##_7 = wp[((i)*8+7)*64];

#define DECLP32(f) unsigned int \
  f##_0,f##_1,f##_2,f##_3,f##_4,f##_5,f##_6,f##_7, \
  f##_8,f##_9,f##_10,f##_11,f##_12,f##_13,f##_14,f##_15, \
  f##_16,f##_17,f##_18,f##_19,f##_20,f##_21,f##_22,f##_23, \
  f##_24,f##_25,f##_26,f##_27,f##_28,f##_29,f##_30,f##_31;

#define AW(dst, src) asm("v_accvgpr_write_b32 %0, %1" : "=a"(dst) : "v"(src))

#define LV(qb, f, a, b, cc, d) { \
  uint4 t = vp[(qb) * 512]; \
  AW(f##_##a, t.x); AW(f##_##b, t.y); AW(f##_##cc, t.z); AW(f##_##d, t.w); }

// one k-chunk: A-frag bcast + 3 MFMA, then 4 h-pairs x 3 outputs on VALU
#define CHUNK(kc, p0, p1, p2, p3) { \
  half8 af = *reinterpret_cast<const half8*>( \
      hb + (((kc) >> 1) * 144 + ((kc) & 1) * 64) + loff); \
  uint4 hraw = *reinterpret_cast<const uint4*>(hb + cOff + (kc) * 16); \
  acc0 = MFMA16(af, B0_##kc, acc0); \
  acc1 = MFMA16(af, B1_##kc, acc1); \
  acc2 = MFMA16(af, B2_##kc, acc2); \
  f16x2 hp0 = __builtin_bit_cast(f16x2, hraw.x); \
  f16x2 hp1 = __builtin_bit_cast(f16x2, hraw.y); \
  f16x2 hp2 = __builtin_bit_cast(f16x2, hraw.z); \
  f16x2 hp3 = __builtin_bit_cast(f16x2, hraw.w); \
  d0 = fdot2f(aread_dep(P0_##p0, hraw.x), hp0, d0); \
  d1 = fdot2f(aread_dep(P1_##p0, hraw.x), hp0, d1); \
  d2 = fdot2f(aread_dep(P2_##p0, hraw.x), hp0, d2); \
  d0 = fdot2f(aread_dep(P0_##p1, hraw.y), hp1, d0); \
  d1 = fdot2f(aread_dep(P1_##p1, hraw.y), hp1, d1); \
  d2 = fdot2f(aread_dep(P2_##p1, hraw.y), hp1, d2); \
  d0 = fdot2f(aread_dep(P0_##p2, hraw.z), hp2, d0); \
  d1 = fdot2f(aread_dep(P1_##p2, hraw.z), hp2, d1); \
  d2 = fdot2f(aread_dep(P2_##p2, hraw.z), hp2, d2); \
  d0 = fdot2f(aread_dep(P0_##p3, hraw.w), hp3, d0); \
  d1 = fdot2f(aread_dep(P1_##p3, hraw.w), hp3, d1); \
  d2 = fdot2f(aread_dep(P2_##p3, hraw.w), hp3, d2); }

__global__ __attribute__((amdgpu_flat_work_group_size(512, 512)))
void scan_kernel(
    const half8* __restrict__ wB,     // layer cache: frags [ch][0..12287] + pairs [ch][12288..]
    const float* __restrict__ bn_,    // [NCH,256]
    const float* __restrict__ log_s,  // [NCH]
    const float* __restrict__ ig,     // [T, 3072]
    const float* __restrict__ h0,     // [256]
    float* __restrict__ y)            // [T, 1024]
{
  const int ch = blockIdx.x;
  const int j  = threadIdx.x;
  const int w  = j >> 6, l = j & 63;
  const int s    = j >> 2;            // VALU output slot 0..127
  const int cOff = (j & 3) * 144;     // VALU k-quarter byte base
  const int loff = (l >> 4) * 16;     // A-frag lane byte offset
  const float* igc = ig + ch * 768;
  float* yc        = y + ch * GHH;

  // MFMA fragments (rows 0..383): 24 half8 = 96 AGPR (native MFMA home)
  const half8* wp = wB + (size_t)ch * 24576 + (size_t)(w * 24) * 64 + l;
  DECLB(0) DECLB(1) DECLB(2)
  LOADB(0) LOADB(1) LOADB(2)

  // VALU pairs (rows 384..767): 96 uints, AGPR-homed via accvgpr_write defs
  const uint4* vp = reinterpret_cast<const uint4*>(wB) +
                    (size_t)ch * 24576 + 12288 + j;
  DECLP32(P0) DECLP32(P1) DECLP32(P2)
  LV(0,P0,0,1,2,3)    LV(1,P0,4,5,6,7)    LV(2,P0,8,9,10,11)
  LV(3,P0,12,13,14,15) LV(4,P0,16,17,18,19) LV(5,P0,20,21,22,23)
  LV(6,P0,24,25,26,27) LV(7,P0,28,29,30,31)
  LV(8,P1,0,1,2,3)    LV(9,P1,4,5,6,7)    LV(10,P1,8,9,10,11)
  LV(11,P1,12,13,14,15) LV(12,P1,16,17,18,19) LV(13,P1,20,21,22,23)
  LV(14,P1,24,25,26,27) LV(15,P1,28,29,30,31)
  LV(16,P2,0,1,2,3)   LV(17,P2,4,5,6,7)   LV(18,P2,8,9,10,11)
  LV(19,P2,12,13,14,15) LV(20,P2,16,17,18,19) LV(21,P2,20,21,22,23)
  LV(22,P2,24,25,26,27) LV(23,P2,28,29,30,31)

  // h: 4 quarters x 144B (128B data + 16B pad -> quarter bases on distinct banks)
  __shared__ __align__(16) unsigned char hslb[576];
  __shared__ float hg[768];
  char* hb = (char*)hslb;

  const bool gate = (j < 256);
  float ls = log_s[ch];
  ls = fminf(fmaxf(ls, -10.f), 10.f);
  const float inv_s = __expf(-ls);
  float bnj = 0.f, h = 0.f, ir = 0.f, iz = 0.f, in_ = 0.f;
  if (gate) {
    h   = h0[j];
    bnj = bn_[ch * GHH + j];
    *reinterpret_cast<_Float16*>(hb + (j >> 6) * 144 + (j & 63) * 2) = (_Float16)h;
    ir = igc[j]; iz = igc[256 + j]; in_ = igc[512 + j];
  }
  SCAN_BAR();

  for (int t = 0; t < T_SEQ; ++t) {
    float nr = 0.f, nz = 0.f, nn = 0.f;
    if (gate && t + 1 < T_SEQ) {
      const float* p = igc + (size_t)(t + 1) * LD_IG;
      nr = p[j]; nz = p[256 + j]; nn = p[512 + j];
    }
    f32x4 acc0 = {0.f, 0.f, 0.f, 0.f}, acc1 = acc0, acc2 = acc0;
    float d0 = 0.f, d1 = 0.f, d2 = 0.f;
    CHUNK(0, 0, 1, 2, 3)    CHUNK(1, 4, 5, 6, 7)
    CHUNK(2, 8, 9, 10, 11)  CHUNK(3, 12, 13, 14, 15)
    CHUNK(4, 16, 17, 18, 19) CHUNK(5, 20, 21, 22, 23)
    CHUNK(6, 24, 25, 26, 27) CHUNK(7, 28, 29, 30, 31)
    // VALU half: reduce 4 k-quarters within each lane-quad (VALU pipe)
    d0 = dpp_xor_add<0xB1>(d0); d1 = dpp_xor_add<0xB1>(d1); d2 = dpp_xor_add<0xB1>(d2);
    d0 = dpp_xor_add<0x4E>(d0); d1 = dpp_xor_add<0x4E>(d1); d2 = dpp_xor_add<0x4E>(d2);
    if ((j & 3) == 0) {
      hg[384 + s] = d0; hg[512 + s] = d1; hg[640 + s] = d2;
    }
    // MFMA half: D col n = lane&15; uniform-A -> reg 0 holds hg[block*16+n]
    if (l < 16) {
      hg[w * 48 + l]      = acc0[0];
      hg[w * 48 + 16 + l] = acc1[0];
      hg[w * 48 + 32 + l] = acc2[0];
    }
    SCAN_BAR();
    if (gate) {
      const float hr = hg[j], hz = hg[256 + j], hn = hg[512 + j];
      const float rg = sigmoid_f(ir + hr);
      const float zg = sigmoid_f(iz + hz);
      const float ng = tanh_f(in_ + rg * (hn + bnj));
      const float hnew = ng + zg * (h - ng);
      h = (hnew - h) * inv_s + h;
      yc[(size_t)t * NST + j] = h;
      *reinterpret_cast<_Float16*>(hb + (j >> 6) * 144 + (j & 63) * 2) = (_Float16)h;
    }
    SCAN_BAR();
    ir = nr; iz = nz; in_ = nn;
  }
}

// ---------------------------------------------------------------------------
// Classifier second GEMM: N=10, K=1024. One block per row (unchanged).
// ---------------------------------------------------------------------------
__global__ __launch_bounds__(256) void gemv_cls(const float* __restrict__ A,
                                                const float* __restrict__ W,
                                                const float* __restrict__ b,
                                                float* __restrict__ out)
{
  const int m = blockIdx.x, t = threadIdx.x;
  float4 a = reinterpret_cast<const float4*>(A + (size_t)m * NST)[t];
  float p[10];
#pragma unroll
  for (int n = 0; n < 10; ++n) {
    float4 w = reinterpret_cast<const float4*>(W + (size_t)n * NST)[t];
    p[n] = a.x * w.x + a.y * w.y + a.z * w.z + a.w * w.w;
  }
#pragma unroll
  for (int n = 0; n < 10; ++n)
#pragma unroll
    for (int msk = 1; msk < 64; msk <<= 1) p[n] += __shfl_xor(p[n], msk, 64);
  __shared__ float red[4][10];
  const int wv = t >> 6;
  if ((t & 63) == 0) {
#pragma unroll
    for (int n = 0; n < 10; ++n) red[wv][n] = p[n];
  }
  __syncthreads();
  if (t < 10) {
    float v = red[0][t] + red[1][t] + red[2][t] + red[3][t] + b[t];
    out[(size_t)m * 10 + t] = v;
  }
}

// ---------------------------------------------------------------------------
extern "C" void kernel_launch(void* const* d_in, const int* in_sizes, int n_in,
                              void* d_out, int out_size, void* d_ws, size_t ws_size,
                              hipStream_t stream) {
  const float* inputs = (const float*)d_in[0];
  const float* h0     = (const float*)d_in[1];
  // d_in[2] = yinit_guess: unused (exact solution independent of it)
  const float* enc_w1 = (const float*)d_in[3];
  const float* enc_b1 = (const float*)d_in[4];
  const float* enc_w2 = (const float*)d_in[5];
  const float* enc_b2 = (const float*)d_in[6];
  const float* gwih   = (const float*)d_in[7];   // [3,4,768,1024]
  const float* gwhh   = (const float*)d_in[8];   // [3,4,768,256]
  const float* gb     = (const float*)d_in[9];   // [3,4,768]
  const float* gbn    = (const float*)d_in[10];  // [3,4,256]
  const float* gls    = (const float*)d_in[11];  // [3,4,1]
  const float* mw1    = (const float*)d_in[12];
  const float* mb1    = (const float*)d_in[13];
  const float* mw2    = (const float*)d_in[14];
  const float* mb2    = (const float*)d_in[15];
  const float* cw1    = (const float*)d_in[16];
  const float* cb1    = (const float*)d_in[17];
  const float* cw2    = (const float*)d_in[18];
  const float* cb2    = (const float*)d_in[19];
  float* out = (float*)d_out;

  char* ws = (char*)d_ws;
  float* bufA = (float*)ws;                          // [8192,1024] 33.5MB
  float* bufB = (float*)(ws + (size_t)33554432);     // [8192,1024] 33.5MB
  float* bufG = (float*)(ws + (size_t)67108864);     // [8192,3072] 100.7MB (ig / mlp hidden)
  half8* gw16 = (half8*)(ws + (size_t)GW_OFF);       // weight cache, 4.7MB (frags + pairs)

  const dim3 blk(256);
  const dim3 gemm_1024(8192 / 64, 1024 / 64);
  const dim3 gemm_3072(8192 / 64, 3072 / 64);

  // weight caches (ordered before first scan; disjoint halves of gw16)
  prep_whh<<<dim3(576), blk, 0, stream>>>(gwhh, gw16);
  prep_vw<<<dim3(2304), blk, 0, stream>>>(gwhh, (unsigned int*)gw16);

  // encoder
  gemm_f32<0, true ><<<gemm_1024, blk, 0, stream>>>(inputs, enc_w1, enc_b1, nullptr,
                                                    bufG, 8192, 1024, 128, nullptr);
  gemm_f32<0, false><<<gemm_1024, blk, 0, stream>>>(bufG, enc_w2, enc_b2, nullptr,
                                                    bufA, 8192, 1024, 1024, nullptr);
  float* x  = bufA;
  float* xb = bufB;
  for (int i = 0; i < 3; ++i) {
    ln_kernel<false><<<dim3(8192), blk, 0, stream>>>(x, nullptr, xb);
    gemm_f32<1, false><<<gemm_3072, blk, 0, stream>>>(xb, gwih + (size_t)i * 4 * 768 * 1024,
                                                      gb + (size_t)i * 3072, nullptr,
                                                      bufG, 8192, 3072, 1024,
                                                      gls + (size_t)i * 4);
    scan_kernel<<<dim3(4), dim3(512), 0, stream>>>(gw16 + (size_t)i * 98304,
                                                   gbn + (size_t)i * 1024,
                                                   gls + (size_t)i * 4,
                                                   bufG, h0, x);
    ln_kernel<true><<<dim3(8192), blk, 0, stream>>>(x, xb, x);
    gemm_f32<0, true ><<<gemm_1024, blk, 0, stream>>>(x, mw1 + (size_t)i * 1048576,
                                                      mb1 + (size_t)i * 1024, nullptr,
                                                      bufG, 8192, 1024, 1024, nullptr);
    gemm_f32<2, false><<<gemm_1024, blk, 0, stream>>>(bufG, mw2 + (size_t)i * 1048576,
                                                      mb2 + (size_t)i * 1024, x,
                                                      xb, 8192, 1024, 1024, nullptr);
    float* tmp = x; x = xb; xb = tmp;
  }
  // classifier
  gemm_f32<0, true><<<gemm_1024, blk, 0, stream>>>(x, cw1, cb1, nullptr,
                                                   bufG, 8192, 1024, 1024, nullptr);
  gemv_cls<<<dim3(8192), blk, 0, stream>>>(bufG, cw2, cb2, out);
}

// Round 10
// 16784.619 us; speedup vs baseline: 2.7894x; 2.7894x over previous
//
#include <hip/hip_runtime.h>

// MultiScaleGRU: T=8192, NINP=128, NSTATE=1024, NCH=4, GH=256, NLAYER=3, NCLASS=10
#define T_SEQ  8192
#define NST    1024
#define GHH    256
#define LD_IG  3072      // 4 channels * 768 ig columns
#define C_CH   1024      // pipeline chunk length
#define NCHUNK 8
#define NDIAG  10        // NCHUNK + NLAYER - 1

typedef _Float16 half8 __attribute__((ext_vector_type(8)));
typedef float f32x4 __attribute__((ext_vector_type(4)));

#define MFMA16(a, b, c) __builtin_amdgcn_mfma_f32_16x16x32_f16(a, b, c, 0, 0, 0)

__device__ __forceinline__ float sigmoid_f(float x) {
  return 1.0f / (1.0f + __expf(-x));
}
__device__ __forceinline__ float tanh_f(float x) {
  float ax = fabsf(x);
  float e = __expf(-2.0f * ax);
  float t = (1.0f - e) / (1.0f + e);
  return copysignf(t, x);
}

// ---------------------------------------------------------------------------
// Prep: whh [3,4,768,256] f32 -> f16 MFMA B-fragment cache (R7-verified).
// Frag (lc, g_id=nb*8+kc, lane l, elem e): n=l&15 -> row nb*16+n,
// k=(l>>4)*8+e -> col kc*32+k.
// ---------------------------------------------------------------------------
__global__ __launch_bounds__(256) void prep_whh(const float* __restrict__ whh,
                                                half8* __restrict__ wB)
{
  const int idx = blockIdx.x * 256 + threadIdx.x;   // 0 .. 294911
  const int lc  = idx / 24576;                      // layer*4+ch
  const int rem = idx - lc * 24576;
  const int g_id = rem >> 6, l = rem & 63;
  const int nb = g_id >> 3, kc = g_id & 7;
  const int g = nb >> 4, ub = nb & 15;
  const int n = l & 15, kg = l >> 4;
  const int row = g * 256 + ub * 16 + n;
  const int col = kc * 32 + kg * 8;
  const float* src = whh + (size_t)lc * 196608 + (size_t)row * 256 + col;
  float4 x0 = *reinterpret_cast<const float4*>(src);
  float4 x1 = *reinterpret_cast<const float4*>(src + 4);
  half8 o;
  o[0] = (_Float16)x0.x; o[1] = (_Float16)x0.y;
  o[2] = (_Float16)x0.z; o[3] = (_Float16)x0.w;
  o[4] = (_Float16)x1.x; o[5] = (_Float16)x1.y;
  o[6] = (_Float16)x1.z; o[7] = (_Float16)x1.w;
  wB[idx] = o;
}

// ---------------------------------------------------------------------------
// f32 tiled GEMM (unchanged): C[M,N] = epi(A[M,K] @ W[N,K]^T).
// ---------------------------------------------------------------------------
template<int EPI, bool RELU>
__global__ __launch_bounds__(256) void gemm_f32(
    const float* __restrict__ A, const float* __restrict__ W,
    const float* __restrict__ bias, const float* __restrict__ R,
    float* __restrict__ C, int M, int N, int K,
    const float* __restrict__ log_s)
{
  const int BM = 64, BN = 64, BK = 16;
  __shared__ float As[BK][BM + 4];
  __shared__ float Ws[BK][BN + 4];
  const int bm = blockIdx.x * BM, bn = blockIdx.y * BN;
  const int t = threadIdx.x;
  const int tx = t & 15, ty = t >> 4;
  const int lm = t >> 2, lk = (t & 3) << 2;

  float acc[4][4] = {};
  const float* Ap = A + (size_t)(bm + lm) * K + lk;
  const float* Wp = W + (size_t)(bn + lm) * K + lk;

  for (int k0 = 0; k0 < K; k0 += BK) {
    float4 av = *reinterpret_cast<const float4*>(Ap + k0);
    float4 wv = *reinterpret_cast<const float4*>(Wp + k0);
    As[lk + 0][lm] = av.x; As[lk + 1][lm] = av.y;
    As[lk + 2][lm] = av.z; As[lk + 3][lm] = av.w;
    Ws[lk + 0][lm] = wv.x; Ws[lk + 1][lm] = wv.y;
    Ws[lk + 2][lm] = wv.z; Ws[lk + 3][lm] = wv.w;
    __syncthreads();
#pragma unroll
    for (int kk = 0; kk < BK; ++kk) {
      float4 a4 = *reinterpret_cast<const float4*>(&As[kk][ty << 2]);
      float4 w4 = *reinterpret_cast<const float4*>(&Ws[kk][tx << 2]);
      float a[4] = {a4.x, a4.y, a4.z, a4.w};
      float w[4] = {w4.x, w4.y, w4.z, w4.w};
#pragma unroll
      for (int i = 0; i < 4; ++i)
#pragma unroll
        for (int jj = 0; jj < 4; ++jj)
          acc[i][jj] = fmaf(a[i], w[jj], acc[i][jj]);
    }
    __syncthreads();
  }

  const int n0 = bn + (tx << 2);
  float b4[4];
#pragma unroll
  for (int jj = 0; jj < 4; ++jj) b4[jj] = bias[n0 + jj];
  float scale = 1.f;
  if (EPI == 1) {
    int chn = n0 / 768;
    float ls = log_s[chn];
    ls = fminf(fmaxf(ls, -10.f), 10.f);
    scale = __expf(-ls);
  }
#pragma unroll
  for (int i = 0; i < 4; ++i) {
    const int m = bm + (ty << 2) + i;
    float vals[4];
    float4 r4;
    if (EPI == 2) r4 = *reinterpret_cast<const float4*>(R + (size_t)m * N + n0);
#pragma unroll
    for (int jj = 0; jj < 4; ++jj) {
      float v = acc[i][jj];
      if (EPI == 1) v *= scale;
      v += b4[jj];
      if (EPI == 2) v += (jj == 0 ? r4.x : jj == 1 ? r4.y : jj == 2 ? r4.z : r4.w);
      if (RELU) v = fmaxf(v, 0.f);
      vals[jj] = v;
    }
    float4 o; o.x = vals[0]; o.y = vals[1]; o.z = vals[2]; o.w = vals[3];
    *reinterpret_cast<float4*>(C + (size_t)m * N + n0) = o;
  }
}

// ---------------------------------------------------------------------------
// LayerNorm over 1024 features, one block per row (unchanged).
// ---------------------------------------------------------------------------
template<bool ADD>
__global__ __launch_bounds__(256) void ln_kernel(const float* __restrict__ X,
                                                 const float* __restrict__ Yad,
                                                 float* __restrict__ O)
{
  const int row = blockIdx.x, t = threadIdx.x;
  float4 v = reinterpret_cast<const float4*>(X + (size_t)row * NST)[t];
  if (ADD) {
    float4 w = reinterpret_cast<const float4*>(Yad + (size_t)row * NST)[t];
    v.x += w.x; v.y += w.y; v.z += w.z; v.w += w.w;
  }
  float s  = v.x + v.y + v.z + v.w;
  float ss = v.x * v.x + v.y * v.y + v.z * v.z + v.w * v.w;
#pragma unroll
  for (int m = 1; m < 64; m <<= 1) {
    s  += __shfl_xor(s, m, 64);
    ss += __shfl_xor(ss, m, 64);
  }
  __shared__ float ps[4], pss[4];
  const int wv = t >> 6;
  if ((t & 63) == 0) { ps[wv] = s; pss[wv] = ss; }
  __syncthreads();
  s  = ps[0] + ps[1] + ps[2] + ps[3];
  ss = pss[0] + pss[1] + pss[2] + pss[3];
  const float mean = s * (1.f / 1024.f);
  const float var  = ss * (1.f / 1024.f) - mean * mean;
  const float rstd = rsqrtf(var + 1e-5f);
  v.x = (v.x - mean) * rstd; v.y = (v.y - mean) * rstd;
  v.z = (v.z - mean) * rstd; v.w = (v.w - mean) * rstd;
  reinterpret_cast<float4*>(O + (size_t)row * NST)[t] = v;
}

// ---------------------------------------------------------------------------
// Fused double-LN: O = LN(Y + LN(X)) per row. Recomputes xi on the fly so the
// pipeline never stores xi (saves 100MB of ws and one pass).
// ---------------------------------------------------------------------------
__global__ __launch_bounds__(256) void ln2_kernel(const float* __restrict__ Y,
                                                  const float* __restrict__ X,
                                                  float* __restrict__ O)
{
  const int row = blockIdx.x, t = threadIdx.x;
  const int wv = t >> 6;
  __shared__ float ps[4], pss[4], ps2[4], pss2[4];

  float4 xv = reinterpret_cast<const float4*>(X + (size_t)row * NST)[t];
  float s  = xv.x + xv.y + xv.z + xv.w;
  float ss = xv.x * xv.x + xv.y * xv.y + xv.z * xv.z + xv.w * xv.w;
#pragma unroll
  for (int m = 1; m < 64; m <<= 1) {
    s += __shfl_xor(s, m, 64); ss += __shfl_xor(ss, m, 64);
  }
  if ((t & 63) == 0) { ps[wv] = s; pss[wv] = ss; }
  __syncthreads();
  s = ps[0] + ps[1] + ps[2] + ps[3];
  ss = pss[0] + pss[1] + pss[2] + pss[3];
  float mean = s * (1.f / 1024.f);
  float var  = ss * (1.f / 1024.f) - mean * mean;
  float rstd = rsqrtf(var + 1e-5f);

  float4 yv = reinterpret_cast<const float4*>(Y + (size_t)row * NST)[t];
  float4 v;
  v.x = yv.x + (xv.x - mean) * rstd;
  v.y = yv.y + (xv.y - mean) * rstd;
  v.z = yv.z + (xv.z - mean) * rstd;
  v.w = yv.w + (xv.w - mean) * rstd;

  s  = v.x + v.y + v.z + v.w;
  ss = v.x * v.x + v.y * v.y + v.z * v.z + v.w * v.w;
#pragma unroll
  for (int m = 1; m < 64; m <<= 1) {
    s += __shfl_xor(s, m, 64); ss += __shfl_xor(ss, m, 64);
  }
  if ((t & 63) == 0) { ps2[wv] = s; pss2[wv] = ss; }
  __syncthreads();
  s = ps2[0] + ps2[1] + ps2[2] + ps2[3];
  ss = pss2[0] + pss2[1] + pss2[2] + pss2[3];
  mean = s * (1.f / 1024.f);
  var  = ss * (1.f / 1024.f) - mean * mean;
  rstd = rsqrtf(var + 1e-5f);
  v.x = (v.x - mean) * rstd; v.y = (v.y - mean) * rstd;
  v.z = (v.z - mean) * rstd; v.w = (v.w - mean) * rstd;
  reinterpret_cast<float4*>(O + (size_t)row * NST)[t] = v;
}

// ---------------------------------------------------------------------------
// ScaleGRU scan — DIAGONAL version of the R7-verified MFMA scan.
// grid=12: block (lidx = bid>>2, ch = bid&3) processes chunk c = d - lidx of
// layer lidx (inactive pairs exit). 512 threads, 8 waves; wave w owns output
// blocks nb = w*6..w*6+5; weights = 48 half8 B-frags = 192 AGPR (the ONLY
// allocator-stable big live set: MFMA operands consumed by MFMA; R8/R9's
// manual AGPR paths both collapsed to scratch). A = h uniform across rows
// (LDS broadcast); D col = lane&15. h carried across chunks in f32 via hst.
// ---------------------------------------------------------------------------
#define SCAN_BAR() asm volatile("s_waitcnt lgkmcnt(0)\n\ts_barrier" ::: "memory")

#define DECLB(i) half8 B##i##_0, B##i##_1, B##i##_2, B##i##_3, \
                       B##i##_4, B##i##_5, B##i##_6, B##i##_7;
#define LOADB(i) \
  B##i##_0 = wp[((i)*8+0)*64]; B##i##_1 = wp[((i)*8+1)*64]; \
  B##i##_2 = wp[((i)*8+2)*64]; B##i##_3 = wp[((i)*8+3)*64]; \
  B##i##_4 = wp[((i)*8+4)*64]; B##i##_5 = wp[((i)*8+5)*64]; \
  B##i##_6 = wp[((i)*8+6)*64]; B##i##_7 = wp[((i)*8+7)*64];

#define KCSTEP(kc) { \
  half8 a = hp[(kc) * 4]; \
  a0 = MFMA16(a, B0_##kc, a0); a1 = MFMA16(a, B1_##kc, a1); \
  a2 = MFMA16(a, B2_##kc, a2); a3 = MFMA16(a, B3_##kc, a3); \
  a4 = MFMA16(a, B4_##kc, a4); a5 = MFMA16(a, B5_##kc, a5); }

__global__ __attribute__((amdgpu_flat_work_group_size(512, 512)))
void scan_diag(
    const half8* __restrict__ wB,     // frag cache [3*4][384][64]
    const float* __restrict__ gbn,    // [3,4,256]
    const float* __restrict__ gls,    // [3,4]
    const float* __restrict__ igb,    // [3][C_CH,3072]
    const float* __restrict__ h0,     // [256]
    float* __restrict__ hst,          // [3*4*256] carried h state
    float* __restrict__ yb,           // [3][C_CH,1024]
    int d)
{
  const int lidx = blockIdx.x >> 2;
  const int ch   = blockIdx.x & 3;
  const int c    = d - lidx;
  if (c < 0 || c >= NCHUNK) return;

  const int j = threadIdx.x;
  const int w = j >> 6, l = j & 63;
  const int lc = lidx * 4 + ch;
  const float* igc = igb + (size_t)lidx * (C_CH * LD_IG) + ch * 768;
  float* yc        = yb + (size_t)lidx * (C_CH * NST) + ch * GHH;

  const half8* wp = wB + (size_t)lc * 24576 + (size_t)(w * 48) * 64 + l;
  DECLB(0) DECLB(1) DECLB(2) DECLB(3) DECLB(4) DECLB(5)
  LOADB(0) LOADB(1) LOADB(2) LOADB(3) LOADB(4) LOADB(5)

  __shared__ __align__(16) _Float16 hsl[GHH];  // h, f16
  __shared__ float hg[768];                    // Whh*h results

  const bool gate = (j < 256);
  float ls = gls[lc];
  ls = fminf(fmaxf(ls, -10.f), 10.f);
  const float inv_s = __expf(-ls);
  float bnj = 0.f, h = 0.f, ir = 0.f, iz = 0.f, in_ = 0.f;
  if (gate) {
    h   = (c == 0) ? h0[j] : hst[lc * GHH + j];
    bnj = gbn[lc * GHH + j];
    hsl[j] = (_Float16)h;
    ir = igc[j]; iz = igc[256 + j]; in_ = igc[512 + j];
  }
  SCAN_BAR();

  const half8* hp = reinterpret_cast<const half8*>(hsl) + (l >> 4);

  for (int t = 0; t < C_CH; ++t) {
    float nr = 0.f, nz = 0.f, nn = 0.f;
    if (gate && t + 1 < C_CH) {
      const float* p = igc + (size_t)(t + 1) * LD_IG;
      nr = p[j]; nz = p[256 + j]; nn = p[512 + j];
    }
    f32x4 a0 = {0.f, 0.f, 0.f, 0.f}, a1 = a0, a2 = a0, a3 = a0, a4 = a0, a5 = a0;
    KCSTEP(0) KCSTEP(1) KCSTEP(2) KCSTEP(3)
    KCSTEP(4) KCSTEP(5) KCSTEP(6) KCSTEP(7)
    if (l < 16) {   // D col n = lane&15; uniform-A -> any row/reg holds hg[n]
      hg[(w * 6 + 0) * 16 + l] = a0[0];
      hg[(w * 6 + 1) * 16 + l] = a1[0];
      hg[(w * 6 + 2) * 16 + l] = a2[0];
      hg[(w * 6 + 3) * 16 + l] = a3[0];
      hg[(w * 6 + 4) * 16 + l] = a4[0];
      hg[(w * 6 + 5) * 16 + l] = a5[0];
    }
    SCAN_BAR();
    if (gate) {
      const float hr = hg[j], hz = hg[256 + j], hn = hg[512 + j];
      const float rg = sigmoid_f(ir + hr);
      const float zg = sigmoid_f(iz + hz);
      const float ng = tanh_f(in_ + rg * (hn + bnj));
      const float hnew = ng + zg * (h - ng);
      h = (hnew - h) * inv_s + h;
      yc[(size_t)t * NST + j] = h;
      hsl[j] = (_Float16)h;
    }
    SCAN_BAR();
    ir = nr; iz = nz; in_ = nn;
  }
  if (gate) hst[lc * GHH + j] = h;   // carry to chunk c+1
}

// ---------------------------------------------------------------------------
// Classifier second GEMM: N=10, K=1024. One block per row (unchanged).
// ---------------------------------------------------------------------------
__global__ __launch_bounds__(256) void gemv_cls(const float* __restrict__ A,
                                                const float* __restrict__ W,
                                                const float* __restrict__ b,
                                                float* __restrict__ out)
{
  const int m = blockIdx.x, t = threadIdx.x;
  float4 a = reinterpret_cast<const float4*>(A + (size_t)m * NST)[t];
  float p[10];
#pragma unroll
  for (int n = 0; n < 10; ++n) {
    float4 w = reinterpret_cast<const float4*>(W + (size_t)n * NST)[t];
    p[n] = a.x * w.x + a.y * w.y + a.z * w.z + a.w * w.w;
  }
#pragma unroll
  for (int n = 0; n < 10; ++n)
#pragma unroll
    for (int msk = 1; msk < 64; msk <<= 1) p[n] += __shfl_xor(p[n], msk, 64);
  __shared__ float red[4][10];
  const int wv = t >> 6;
  if ((t & 63) == 0) {
#pragma unroll
    for (int n = 0; n < 10; ++n) red[wv][n] = p[n];
  }
  __syncthreads();
  if (t < 10) {
    float v = red[0][t] + red[1][t] + red[2][t] + red[3][t] + b[t];
    out[(size_t)m * 10 + t] = v;
  }
}

// ---------------------------------------------------------------------------
extern "C" void kernel_launch(void* const* d_in, const int* in_sizes, int n_in,
                              void* d_out, int out_size, void* d_ws, size_t ws_size,
                              hipStream_t stream) {
  const float* inputs = (const float*)d_in[0];
  const float* h0     = (const float*)d_in[1];
  // d_in[2] = yinit_guess: unused (exact solution independent of it)
  const float* enc_w1 = (const float*)d_in[3];
  const float* enc_b1 = (const float*)d_in[4];
  const float* enc_w2 = (const float*)d_in[5];
  const float* enc_b2 = (const float*)d_in[6];
  const float* gwih   = (const float*)d_in[7];   // [3,4,768,1024]
  const float* gwhh   = (const float*)d_in[8];   // [3,4,768,256]
  const float* gb     = (const float*)d_in[9];   // [3,4,768]
  const float* gbn    = (const float*)d_in[10];  // [3,4,256]
  const float* gls    = (const float*)d_in[11];  // [3,4,1]
  const float* mw1    = (const float*)d_in[12];
  const float* mb1    = (const float*)d_in[13];
  const float* mw2    = (const float*)d_in[14];
  const float* mb2    = (const float*)d_in[15];
  const float* cw1    = (const float*)d_in[16];
  const float* cb1    = (const float*)d_in[17];
  const float* cw2    = (const float*)d_in[18];
  const float* cb2    = (const float*)d_in[19];
  float* out = (float*)d_out;

  // ws layout (bytes) — 126.4MB total, < 172MB proven in R5-R9
  char* ws = (char*)d_ws;
  float* x0    = (float*)(ws);                        // [8192,1024] 33.5MB
  float* xr1   = (float*)(ws + 33554432ull);          // ring [2][C,1024] 8.4MB
  float* xr2   = (float*)(ws + 41943040ull);          // ring [2][C,1024] 8.4MB
  float* igbuf = (float*)(ws + 50331648ull);          // [3][C,3072] 37.7MB (+enc scratch)
  half8* gw16  = (half8*)(ws + 88080384ull);          // frag cache 4.7MB
  float* bufY  = (float*)(ws + 92798976ull);          // [3][C,1024] 12.6MB
  float* bufYn = (float*)(ws + 105381888ull);         // [C,1024] 4.2MB
  float* bufH  = (float*)(ws + 109576192ull);         // [C,1024] 4.2MB
  float* xitmp = (float*)(ws + 113770496ull);         // [C,1024] 4.2MB
  float* xf    = (float*)(ws + 117964800ull);         // [C,1024] 4.2MB
  float* clsH  = (float*)(ws + 122159104ull);         // [C,1024] 4.2MB
  float* hst   = (float*)(ws + 126353408ull);         // [3,4,256] 12KB

  const dim3 blk(256);
  const dim3 g_enc(8192 / 64, 1024 / 64);
  const dim3 g_ig(C_CH / 64, 3072 / 64);
  const dim3 g_mlp(C_CH / 64, 1024 / 64);

  // x chunk pointer: layer 0 = full buffer; layers 1,2 = depth-2 rings
  auto xptr = [&](int lth, int c) -> float* {
    if (lth == 0) return x0 + (size_t)c * C_CH * NST;
    float* base = (lth == 1) ? xr1 : xr2;
    return base + (size_t)(c & 1) * C_CH * NST;
  };

  // weight frag cache (all 3 layers)
  prep_whh<<<dim3(1152), blk, 0, stream>>>(gwhh, gw16);

  // encoder (full T): hidden in igbuf scratch (free until diagonal 0's pre)
  gemm_f32<0, true ><<<g_enc, blk, 0, stream>>>(inputs, enc_w1, enc_b1, nullptr,
                                                (float*)igbuf, 8192, 1024, 128, nullptr);
  gemm_f32<0, false><<<g_enc, blk, 0, stream>>>((float*)igbuf, enc_w2, enc_b2, nullptr,
                                                x0, 8192, 1024, 1024, nullptr);

  for (int d = 0; d < NDIAG; ++d) {
    // --- pre: ig(l, c) for every pair active at diagonal d ---
    for (int lth = 0; lth < 3; ++lth) {
      const int c = d - lth;
      if (c < 0 || c >= NCHUNK) continue;
      ln_kernel<false><<<dim3(C_CH), blk, 0, stream>>>(xptr(lth, c), nullptr, xitmp);
      gemm_f32<1, false><<<g_ig, blk, 0, stream>>>(
          xitmp, gwih + (size_t)lth * 4 * 768 * 1024, gb + (size_t)lth * 3072,
          nullptr, igbuf + (size_t)lth * C_CH * LD_IG, C_CH, 3072, 1024,
          gls + (size_t)lth * 4);
    }
    // --- scan diagonal: up to 12 (layer,channel) blocks in parallel ---
    scan_diag<<<dim3(12), dim3(512), 0, stream>>>(gw16, gbn, gls, igbuf,
                                                  h0, hst, bufY, d);
    // --- post: y -> next layer input (or classifier) per active pair ---
    for (int lth = 0; lth < 3; ++lth) {
      const int c = d - lth;
      if (c < 0 || c >= NCHUNK) continue;
      ln2_kernel<<<dim3(C_CH), blk, 0, stream>>>(
          bufY + (size_t)lth * C_CH * NST, xptr(lth, c), bufYn);
      gemm_f32<0, true ><<<g_mlp, blk, 0, stream>>>(
          bufYn, mw1 + (size_t)lth * 1048576, mb1 + (size_t)lth * 1024,
          nullptr, bufH, C_CH, 1024, 1024, nullptr);
      float* xnext = (lth < 2) ? xptr(lth + 1, c) : xf;
      gemm_f32<2, false><<<g_mlp, blk, 0, stream>>>(
          bufH, mw2 + (size_t)lth * 1048576, mb2 + (size_t)lth * 1024,
          bufYn, xnext, C_CH, 1024, 1024, nullptr);
      if (lth == 2) {   // classifier on this finished chunk
        gemm_f32<0, true><<<g_mlp, blk, 0, stream>>>(
            xf, cw1, cb1, nullptr, clsH, C_CH, 1024, 1024, nullptr);
        gemv_cls<<<dim3(C_CH), blk, 0, stream>>>(clsH, cw2, cb2,
                                                 out + (size_t)c * C_CH * 10);
      }
    }
  }
}

// Round 11
// 13282.843 us; speedup vs baseline: 3.5247x; 1.2636x over previous
//
#include <hip/hip_runtime.h>

// MultiScaleGRU: T=8192, NINP=128, NSTATE=1024, NCH=4, GH=256, NLAYER=3, NCLASS=10
#define T_SEQ  8192
#define NST    1024
#define GHH    256
#define LD_IG  3072      // 4 channels * 768 ig columns
#define C_CH   1024      // pipeline chunk length
#define NCHUNK 8
#define NDIAG  10        // NCHUNK + NLAYER - 1

typedef _Float16 half8 __attribute__((ext_vector_type(8)));
typedef float f32x4 __attribute__((ext_vector_type(4)));

#define MFMA16(a, b, c) __builtin_amdgcn_mfma_f32_16x16x32_f16(a, b, c, 0, 0, 0)

__device__ __forceinline__ float sigmoid_f(float x) {
  return 1.0f / (1.0f + __expf(-x));
}
__device__ __forceinline__ float tanh_f(float x) {
  float ax = fabsf(x);
  float e = __expf(-2.0f * ax);
  float t = (1.0f - e) / (1.0f + e);
  return copysignf(t, x);
}

// ---------------------------------------------------------------------------
// Prep: whh [3,4,768,256] f32 -> f16 MFMA B-fragment cache (R7/R10-verified).
// ---------------------------------------------------------------------------
__global__ __launch_bounds__(256) void prep_whh(const float* __restrict__ whh,
                                                half8* __restrict__ wB)
{
  const int idx = blockIdx.x * 256 + threadIdx.x;   // 0 .. 294911
  const int lc  = idx / 24576;                      // layer*4+ch
  const int rem = idx - lc * 24576;
  const int g_id = rem >> 6, l = rem & 63;
  const int nb = g_id >> 3, kc = g_id & 7;
  const int g = nb >> 4, ub = nb & 15;
  const int n = l & 15, kg = l >> 4;
  const int row = g * 256 + ub * 16 + n;
  const int col = kc * 32 + kg * 8;
  const float* src = whh + (size_t)lc * 196608 + (size_t)row * 256 + col;
  float4 x0 = *reinterpret_cast<const float4*>(src);
  float4 x1 = *reinterpret_cast<const float4*>(src + 4);
  half8 o;
  o[0] = (_Float16)x0.x; o[1] = (_Float16)x0.y;
  o[2] = (_Float16)x0.z; o[3] = (_Float16)x0.w;
  o[4] = (_Float16)x1.x; o[5] = (_Float16)x1.y;
  o[6] = (_Float16)x1.z; o[7] = (_Float16)x1.w;
  wB[idx] = o;
}

// ---------------------------------------------------------------------------
// Weight f32 -> f16 converter (row-major, layout-preserving). n8 = elems/8.
// ---------------------------------------------------------------------------
__global__ __launch_bounds__(256) void cvt_to_h(const float* __restrict__ src,
                                                _Float16* __restrict__ dst, int n8)
{
  const int i = blockIdx.x * 256 + threadIdx.x;
  if (i >= n8) return;
  float4 a = reinterpret_cast<const float4*>(src)[2 * i];
  float4 b = reinterpret_cast<const float4*>(src)[2 * i + 1];
  half8 o;
  o[0] = (_Float16)a.x; o[1] = (_Float16)a.y; o[2] = (_Float16)a.z; o[3] = (_Float16)a.w;
  o[4] = (_Float16)b.x; o[5] = (_Float16)b.y; o[6] = (_Float16)b.z; o[7] = (_Float16)b.w;
  reinterpret_cast<half8*>(dst)[i] = o;
}

// ---------------------------------------------------------------------------
// f16-MFMA GEMM: C[M,N] = epi(A[M,K] @ W[N,K]^T). A f32 (cvt on stage),
// Wh pre-converted f16 row-major. 64x64 tile, BK=32, 256 thr = 4 waves
// in 2x2, each wave 32x32 = 2x2 16x16x32 frags. Operand convention is the
// R7/R10-scan-verified one: both frags [16 rows=lane&15][32 k=(l>>4)*8+e];
// D col=lane&15 (B-row), row=(l>>4)*4+reg (A-row). LDS stride 40 halfs
// (80B: 16B-aligned rows; 20-bank step -> worst 2-way alias, free per m136).
// M,N mult of 64; K mult of 32 (holds for all call sites: K=128/1024).
// EPI 0: +bias; 1: *1/s[ch]+bias; 2: +bias+R. RELU last.
// ---------------------------------------------------------------------------
template<int EPI, bool RELU>
__global__ __launch_bounds__(256) void gemm_h(
    const float* __restrict__ A, const _Float16* __restrict__ Wh,
    const float* __restrict__ bias, const float* __restrict__ R,
    float* __restrict__ C, int M, int N, int K,
    const float* __restrict__ log_s)
{
  __shared__ _Float16 As[64][40];
  __shared__ _Float16 Ws[64][40];
  const int t = threadIdx.x;
  const int bm = blockIdx.x * 64, bn = blockIdx.y * 64;
  const int wave = t >> 6, l = t & 63;
  const int wm = (wave & 1) * 32, wn = (wave >> 1) * 32;
  const int sr = t >> 2, sc = (t & 3) * 8;     // staging: row sr, k-chunk sc..sc+7
  const int fr = l & 15, fk = (l >> 4) * 8;    // fragment lane mapping

  f32x4 acc00 = {0.f, 0.f, 0.f, 0.f}, acc01 = acc00, acc10 = acc00, acc11 = acc00;

  const float* Ap     = A  + (size_t)(bm + sr) * K + sc;
  const _Float16* Wp  = Wh + (size_t)(bn + sr) * K + sc;

  for (int k0 = 0; k0 < K; k0 += 32) {
    float4 a0 = *reinterpret_cast<const float4*>(Ap + k0);
    float4 a1 = *reinterpret_cast<const float4*>(Ap + k0 + 4);
    half8 av;
    av[0] = (_Float16)a0.x; av[1] = (_Float16)a0.y;
    av[2] = (_Float16)a0.z; av[3] = (_Float16)a0.w;
    av[4] = (_Float16)a1.x; av[5] = (_Float16)a1.y;
    av[6] = (_Float16)a1.z; av[7] = (_Float16)a1.w;
    *reinterpret_cast<half8*>(&As[sr][sc]) = av;
    *reinterpret_cast<half8*>(&Ws[sr][sc]) =
        *reinterpret_cast<const half8*>(Wp + k0);
    __syncthreads();
    half8 af0 = *reinterpret_cast<const half8*>(&As[wm + fr][fk]);
    half8 af1 = *reinterpret_cast<const half8*>(&As[wm + 16 + fr][fk]);
    half8 bf0 = *reinterpret_cast<const half8*>(&Ws[wn + fr][fk]);
    half8 bf1 = *reinterpret_cast<const half8*>(&Ws[wn + 16 + fr][fk]);
    acc00 = MFMA16(af0, bf0, acc00);
    acc01 = MFMA16(af0, bf1, acc01);
    acc10 = MFMA16(af1, bf0, acc10);
    acc11 = MFMA16(af1, bf1, acc11);
    __syncthreads();
  }

#define EPI_STORE(ac, mi, ni) { \
    const int n_ = bn + wn + (ni) * 16 + fr; \
    const float bv = bias[n_]; \
    float sc_ = 1.f; \
    if (EPI == 1) { \
      float lsv = log_s[n_ / 768]; \
      lsv = fminf(fmaxf(lsv, -10.f), 10.f); \
      sc_ = __expf(-lsv); \
    } \
    _Pragma("unroll") \
    for (int q = 0; q < 4; ++q) { \
      const int m_ = bm + wm + (mi) * 16 + (l >> 4) * 4 + q; \
      float v = ac[q]; \
      if (EPI == 1) v *= sc_; \
      v += bv; \
      if (EPI == 2) v += R[(size_t)m_ * N + n_]; \
      if (RELU) v = fmaxf(v, 0.f); \
      C[(size_t)m_ * N + n_] = v; \
    } }
  EPI_STORE(acc00, 0, 0) EPI_STORE(acc01, 0, 1)
  EPI_STORE(acc10, 1, 0) EPI_STORE(acc11, 1, 1)
#undef EPI_STORE
}

// ---------------------------------------------------------------------------
// LayerNorm over 1024 features, one block per row (unchanged).
// ---------------------------------------------------------------------------
template<bool ADD>
__global__ __launch_bounds__(256) void ln_kernel(const float* __restrict__ X,
                                                 const float* __restrict__ Yad,
                                                 float* __restrict__ O)
{
  const int row = blockIdx.x, t = threadIdx.x;
  float4 v = reinterpret_cast<const float4*>(X + (size_t)row * NST)[t];
  if (ADD) {
    float4 w = reinterpret_cast<const float4*>(Yad + (size_t)row * NST)[t];
    v.x += w.x; v.y += w.y; v.z += w.z; v.w += w.w;
  }
  float s  = v.x + v.y + v.z + v.w;
  float ss = v.x * v.x + v.y * v.y + v.z * v.z + v.w * v.w;
#pragma unroll
  for (int m = 1; m < 64; m <<= 1) {
    s  += __shfl_xor(s, m, 64);
    ss += __shfl_xor(ss, m, 64);
  }
  __shared__ float ps[4], pss[4];
  const int wv = t >> 6;
  if ((t & 63) == 0) { ps[wv] = s; pss[wv] = ss; }
  __syncthreads();
  s  = ps[0] + ps[1] + ps[2] + ps[3];
  ss = pss[0] + pss[1] + pss[2] + pss[3];
  const float mean = s * (1.f / 1024.f);
  const float var  = ss * (1.f / 1024.f) - mean * mean;
  const float rstd = rsqrtf(var + 1e-5f);
  v.x = (v.x - mean) * rstd; v.y = (v.y - mean) * rstd;
  v.z = (v.z - mean) * rstd; v.w = (v.w - mean) * rstd;
  reinterpret_cast<float4*>(O + (size_t)row * NST)[t] = v;
}

// ---------------------------------------------------------------------------
// Fused double-LN: O = LN(Y + LN(X)) per row (unchanged).
// ---------------------------------------------------------------------------
__global__ __launch_bounds__(256) void ln2_kernel(const float* __restrict__ Y,
                                                  const float* __restrict__ X,
                                                  float* __restrict__ O)
{
  const int row = blockIdx.x, t = threadIdx.x;
  const int wv = t >> 6;
  __shared__ float ps[4], pss[4], ps2[4], pss2[4];

  float4 xv = reinterpret_cast<const float4*>(X + (size_t)row * NST)[t];
  float s  = xv.x + xv.y + xv.z + xv.w;
  float ss = xv.x * xv.x + xv.y * xv.y + xv.z * xv.z + xv.w * xv.w;
#pragma unroll
  for (int m = 1; m < 64; m <<= 1) {
    s += __shfl_xor(s, m, 64); ss += __shfl_xor(ss, m, 64);
  }
  if ((t & 63) == 0) { ps[wv] = s; pss[wv] = ss; }
  __syncthreads();
  s = ps[0] + ps[1] + ps[2] + ps[3];
  ss = pss[0] + pss[1] + pss[2] + pss[3];
  float mean = s * (1.f / 1024.f);
  float var  = ss * (1.f / 1024.f) - mean * mean;
  float rstd = rsqrtf(var + 1e-5f);

  float4 yv = reinterpret_cast<const float4*>(Y + (size_t)row * NST)[t];
  float4 v;
  v.x = yv.x + (xv.x - mean) * rstd;
  v.y = yv.y + (xv.y - mean) * rstd;
  v.z = yv.z + (xv.z - mean) * rstd;
  v.w = yv.w + (xv.w - mean) * rstd;

  s  = v.x + v.y + v.z + v.w;
  ss = v.x * v.x + v.y * v.y + v.z * v.z + v.w * v.w;
#pragma unroll
  for (int m = 1; m < 64; m <<= 1) {
    s += __shfl_xor(s, m, 64); ss += __shfl_xor(ss, m, 64);
  }
  if ((t & 63) == 0) { ps2[wv] = s; pss2[wv] = ss; }
  __syncthreads();
  s = ps2[0] + ps2[1] + ps2[2] + ps2[3];
  ss = pss2[0] + pss2[1] + pss2[2] + pss2[3];
  mean = s * (1.f / 1024.f);
  var  = ss * (1.f / 1024.f) - mean * mean;
  rstd = rsqrtf(var + 1e-5f);
  v.x = (v.x - mean) * rstd; v.y = (v.y - mean) * rstd;
  v.z = (v.z - mean) * rstd; v.w = (v.w - mean) * rstd;
  reinterpret_cast<float4*>(O + (size_t)row * NST)[t] = v;
}

// ---------------------------------------------------------------------------
// ScaleGRU scan — diagonal MFMA version (unchanged from R10, verified).
// ---------------------------------------------------------------------------
#define SCAN_BAR() asm volatile("s_waitcnt lgkmcnt(0)\n\ts_barrier" ::: "memory")

#define DECLB(i) half8 B##i##_0, B##i##_1, B##i##_2, B##i##_3, \
                       B##i##_4, B##i##_5, B##i##_6, B##i##_7;
#define LOADB(i) \
  B##i##_0 = wp[((i)*8+0)*64]; B##i##_1 = wp[((i)*8+1)*64]; \
  B##i##_2 = wp[((i)*8+2)*64]; B##i##_3 = wp[((i)*8+3)*64]; \
  B##i##_4 = wp[((i)*8+4)*64]; B##i##_5 = wp[((i)*8+5)*64]; \
  B##i##_6 = wp[((i)*8+6)*64]; B##i##_7 = wp[((i)*8+7)*64];

#define KCSTEP(kc) { \
  half8 a = hp[(kc) * 4]; \
  a0 = MFMA16(a, B0_##kc, a0); a1 = MFMA16(a, B1_##kc, a1); \
  a2 = MFMA16(a, B2_##kc, a2); a3 = MFMA16(a, B3_##kc, a3); \
  a4 = MFMA16(a, B4_##kc, a4); a5 = MFMA16(a, B5_##kc, a5); }

__global__ __attribute__((amdgpu_flat_work_group_size(512, 512)))
void scan_diag(
    const half8* __restrict__ wB,     // frag cache [3*4][384][64]
    const float* __restrict__ gbn,    // [3,4,256]
    const float* __restrict__ gls,    // [3,4]
    const float* __restrict__ igb,    // [3][C_CH,3072]
    const float* __restrict__ h0,     // [256]
    float* __restrict__ hst,          // [3*4*256] carried h state
    float* __restrict__ yb,           // [3][C_CH,1024]
    int d)
{
  const int lidx = blockIdx.x >> 2;
  const int ch   = blockIdx.x & 3;
  const int c    = d - lidx;
  if (c < 0 || c >= NCHUNK) return;

  const int j = threadIdx.x;
  const int w = j >> 6, l = j & 63;
  const int lc = lidx * 4 + ch;
  const float* igc = igb + (size_t)lidx * (C_CH * LD_IG) + ch * 768;
  float* yc        = yb + (size_t)lidx * (C_CH * NST) + ch * GHH;

  const half8* wp = wB + (size_t)lc * 24576 + (size_t)(w * 48) * 64 + l;
  DECLB(0) DECLB(1) DECLB(2) DECLB(3) DECLB(4) DECLB(5)
  LOADB(0) LOADB(1) LOADB(2) LOADB(3) LOADB(4) LOADB(5)

  __shared__ __align__(16) _Float16 hsl[GHH];  // h, f16
  __shared__ float hg[768];                    // Whh*h results

  const bool gate = (j < 256);
  float ls = gls[lc];
  ls = fminf(fmaxf(ls, -10.f), 10.f);
  const float inv_s = __expf(-ls);
  float bnj = 0.f, h = 0.f, ir = 0.f, iz = 0.f, in_ = 0.f;
  if (gate) {
    h   = (c == 0) ? h0[j] : hst[lc * GHH + j];
    bnj = gbn[lc * GHH + j];
    hsl[j] = (_Float16)h;
    ir = igc[j]; iz = igc[256 + j]; in_ = igc[512 + j];
  }
  SCAN_BAR();

  const half8* hp = reinterpret_cast<const half8*>(hsl) + (l >> 4);

  for (int t = 0; t < C_CH; ++t) {
    float nr = 0.f, nz = 0.f, nn = 0.f;
    if (gate && t + 1 < C_CH) {
      const float* p = igc + (size_t)(t + 1) * LD_IG;
      nr = p[j]; nz = p[256 + j]; nn = p[512 + j];
    }
    f32x4 a0 = {0.f, 0.f, 0.f, 0.f}, a1 = a0, a2 = a0, a3 = a0, a4 = a0, a5 = a0;
    KCSTEP(0) KCSTEP(1) KCSTEP(2) KCSTEP(3)
    KCSTEP(4) KCSTEP(5) KCSTEP(6) KCSTEP(7)
    if (l < 16) {   // D col n = lane&15; uniform-A -> any row/reg holds hg[n]
      hg[(w * 6 + 0) * 16 + l] = a0[0];
      hg[(w * 6 + 1) * 16 + l] = a1[0];
      hg[(w * 6 + 2) * 16 + l] = a2[0];
      hg[(w * 6 + 3) * 16 + l] = a3[0];
      hg[(w * 6 + 4) * 16 + l] = a4[0];
      hg[(w * 6 + 5) * 16 + l] = a5[0];
    }
    SCAN_BAR();
    if (gate) {
      const float hr = hg[j], hz = hg[256 + j], hn = hg[512 + j];
      const float rg = sigmoid_f(ir + hr);
      const float zg = sigmoid_f(iz + hz);
      const float ng = tanh_f(in_ + rg * (hn + bnj));
      const float hnew = ng + zg * (h - ng);
      h = (hnew - h) * inv_s + h;
      yc[(size_t)t * NST + j] = h;
      hsl[j] = (_Float16)h;
    }
    SCAN_BAR();
    ir = nr; iz = nz; in_ = nn;
  }
  if (gate) hst[lc * GHH + j] = h;   // carry to chunk c+1
}

// ---------------------------------------------------------------------------
// Classifier second GEMM: N=10, K=1024. One block per row (unchanged).
// ---------------------------------------------------------------------------
__global__ __launch_bounds__(256) void gemv_cls(const float* __restrict__ A,
                                                const float* __restrict__ W,
                                                const float* __restrict__ b,
                                                float* __restrict__ out)
{
  const int m = blockIdx.x, t = threadIdx.x;
  float4 a = reinterpret_cast<const float4*>(A + (size_t)m * NST)[t];
  float p[10];
#pragma unroll
  for (int n = 0; n < 10; ++n) {
    float4 w = reinterpret_cast<const float4*>(W + (size_t)n * NST)[t];
    p[n] = a.x * w.x + a.y * w.y + a.z * w.z + a.w * w.w;
  }
#pragma unroll
  for (int n = 0; n < 10; ++n)
#pragma unroll
    for (int msk = 1; msk < 64; msk <<= 1) p[n] += __shfl_xor(p[n], msk, 64);
  __shared__ float red[4][10];
  const int wv = t >> 6;
  if ((t & 63) == 0) {
#pragma unroll
    for (int n = 0; n < 10; ++n) red[wv][n] = p[n];
  }
  __syncthreads();
  if (t < 10) {
    float v = red[0][t] + red[1][t] + red[2][t] + red[3][t] + b[t];
    out[(size_t)m * 10 + t] = v;
  }
}

// ---------------------------------------------------------------------------
extern "C" void kernel_launch(void* const* d_in, const int* in_sizes, int n_in,
                              void* d_out, int out_size, void* d_ws, size_t ws_size,
                              hipStream_t stream) {
  const float* inputs = (const float*)d_in[0];
  const float* h0     = (const float*)d_in[1];
  // d_in[2] = yinit_guess: unused (exact solution independent of it)
  const float* enc_w1 = (const float*)d_in[3];
  const float* enc_b1 = (const float*)d_in[4];
  const float* enc_w2 = (const float*)d_in[5];
  const float* enc_b2 = (const float*)d_in[6];
  const float* gwih   = (const float*)d_in[7];   // [3,4,768,1024]
  const float* gwhh   = (const float*)d_in[8];   // [3,4,768,256]
  const float* gb     = (const float*)d_in[9];   // [3,4,768]
  const float* gbn    = (const float*)d_in[10];  // [3,4,256]
  const float* gls    = (const float*)d_in[11];  // [3,4,1]
  const float* mw1    = (const float*)d_in[12];
  const float* mb1    = (const float*)d_in[13];
  const float* mw2    = (const float*)d_in[14];
  const float* mb2    = (const float*)d_in[15];
  const float* cw1    = (const float*)d_in[16];
  const float* cb1    = (const float*)d_in[17];
  const float* cw2    = (const float*)d_in[18];
  const float* cb2    = (const float*)d_in[19];
  float* out = (float*)d_out;

  // ws layout (bytes) — tops out at 162.3MB (< 172.5MB proven in R5-R9)
  char* ws = (char*)d_ws;
  float* x0    = (float*)(ws);                        // [8192,1024] 33.5MB
  float* xr1   = (float*)(ws + 33554432ull);          // ring [2][C,1024] 8.4MB
  float* xr2   = (float*)(ws + 41943040ull);          // ring [2][C,1024] 8.4MB
  float* igbuf = (float*)(ws + 50331648ull);          // [3][C,3072] 37.7MB (+enc scratch)
  half8* gw16  = (half8*)(ws + 88080384ull);          // scan frag cache 4.7MB
  float* bufY  = (float*)(ws + 92798976ull);          // [3][C,1024] 12.6MB
  float* bufYn = (float*)(ws + 105381888ull);         // [C,1024] 4.2MB
  float* bufH  = (float*)(ws + 109576192ull);         // [C,1024] 4.2MB
  float* xitmp = (float*)(ws + 113770496ull);         // [C,1024] 4.2MB
  float* xf    = (float*)(ws + 117964800ull);         // [C,1024] 4.2MB
  float* clsH  = (float*)(ws + 122159104ull);         // [C,1024] 4.2MB
  float* hst   = (float*)(ws + 126353408ull);         // [3,4,256] 12KB
  _Float16* wf = (_Float16*)(ws + 126365696ull);      // f16 weights 35.9MB

  // f16 weight sub-offsets (in halfs)
  _Float16* wh_enc1 = wf;                     // 1024x128
  _Float16* wh_enc2 = wf + 131072;            // 1024x1024
  _Float16* wh_wih  = wf + 1179648;           // 3x 3072x1024
  _Float16* wh_mw1  = wf + 10616832;          // 3x 1024x1024
  _Float16* wh_mw2  = wf + 13762560;          // 3x 1024x1024
  _Float16* wh_cw1  = wf + 16908288;          // 1024x1024

  const dim3 blk(256);
  const dim3 g_enc(8192 / 64, 1024 / 64);
  const dim3 g_ig(C_CH / 64, 3072 / 64);
  const dim3 g_mlp(C_CH / 64, 1024 / 64);

  auto xptr = [&](int lth, int c) -> float* {
    if (lth == 0) return x0 + (size_t)c * C_CH * NST;
    float* base = (lth == 1) ? xr1 : xr2;
    return base + (size_t)(c & 1) * C_CH * NST;
  };

  // scan frag cache + GEMM weight conversion
  prep_whh<<<dim3(1152), blk, 0, stream>>>(gwhh, gw16);
  cvt_to_h<<<dim3(64),   blk, 0, stream>>>(enc_w1, wh_enc1, 16384);
  cvt_to_h<<<dim3(512),  blk, 0, stream>>>(enc_w2, wh_enc2, 131072);
  cvt_to_h<<<dim3(4608), blk, 0, stream>>>(gwih,   wh_wih,  1179648);
  cvt_to_h<<<dim3(1536), blk, 0, stream>>>(mw1,    wh_mw1,  393216);
  cvt_to_h<<<dim3(1536), blk, 0, stream>>>(mw2,    wh_mw2,  393216);
  cvt_to_h<<<dim3(512),  blk, 0, stream>>>(cw1,    wh_cw1,  131072);

  // encoder (full T): hidden in igbuf scratch (free until diagonal 0's pre)
  gemm_h<0, true ><<<g_enc, blk, 0, stream>>>(inputs, wh_enc1, enc_b1, nullptr,
                                              (float*)igbuf, 8192, 1024, 128, nullptr);
  gemm_h<0, false><<<g_enc, blk, 0, stream>>>((float*)igbuf, wh_enc2, enc_b2, nullptr,
                                              x0, 8192, 1024, 1024, nullptr);

  for (int d = 0; d < NDIAG; ++d) {
    // --- pre: ig(l, c) for every pair active at diagonal d ---
    for (int lth = 0; lth < 3; ++lth) {
      const int c = d - lth;
      if (c < 0 || c >= NCHUNK) continue;
      ln_kernel<false><<<dim3(C_CH), blk, 0, stream>>>(xptr(lth, c), nullptr, xitmp);
      gemm_h<1, false><<<g_ig, blk, 0, stream>>>(
          xitmp, wh_wih + (size_t)lth * 3145728, gb + (size_t)lth * 3072,
          nullptr, igbuf + (size_t)lth * C_CH * LD_IG, C_CH, 3072, 1024,
          gls + (size_t)lth * 4);
    }
    // --- scan diagonal: up to 12 (layer,channel) blocks in parallel ---
    scan_diag<<<dim3(12), dim3(512), 0, stream>>>(gw16, gbn, gls, igbuf,
                                                  h0, hst, bufY, d);
    // --- post: y -> next layer input (or classifier) per active pair ---
    for (int lth = 0; lth < 3; ++lth) {
      const int c = d - lth;
      if (c < 0 || c >= NCHUNK) continue;
      ln2_kernel<<<dim3(C_CH), blk, 0, stream>>>(
          bufY + (size_t)lth * C_CH * NST, xptr(lth, c), bufYn);
      gemm_h<0, true ><<<g_mlp, blk, 0, stream>>>(
          bufYn, wh_mw1 + (size_t)lth * 1048576, mb1 + (size_t)lth * 1024,
          nullptr, bufH, C_CH, 1024, 1024, nullptr);
      float* xnext = (lth < 2) ? xptr(lth + 1, c) : xf;
      gemm_h<2, false><<<g_mlp, blk, 0, stream>>>(
          bufH, wh_mw2 + (size_t)lth * 1048576, mb2 + (size_t)lth * 1024,
          bufYn, xnext, C_CH, 1024, 1024, nullptr);
      if (lth == 2) {   // classifier on this finished chunk
        gemm_h<0, true><<<g_mlp, blk, 0, stream>>>(
            xf, wh_cw1, cb1, nullptr, clsH, C_CH, 1024, 1024, nullptr);
        gemv_cls<<<dim3(C_CH), blk, 0, stream>>>(clsH, cw2, cb2,
                                                 out + (size_t)c * C_CH * 10);
      }
    }
  }
}